// Round 13
// baseline (4487.333 us; speedup 1.0000x reference)
//
#include <hip/hip_runtime.h>
#include <hip/hip_bf16.h>
#include <stdint.h>

#define BATCH  64
#define SEQ    1024
#define EMBED  128
#define HIDDEN 512
#define VOCAB  256

using bf16 = __hip_bfloat16;
typedef __attribute__((ext_vector_type(8))) short bf16x8;
typedef __attribute__((ext_vector_type(4))) float f32x4;

__device__ __forceinline__ float bfu(unsigned short u) {
    return __uint_as_float(((unsigned)u) << 16);
}

// ---------------- weight converts ----------------
__global__ void k_cvt(const float* __restrict__ in, bf16* __restrict__ out, int n) {
    int i = blockIdx.x * 256 + threadIdx.x;
    if (i < n) out[i] = __float2bfloat16(in[i]);
}

// W_xh [EMBED][HIDDEN] -> wxh_t [HIDDEN][EMBED] bf16
__global__ void k_txp_wxh(const float* __restrict__ in, bf16* __restrict__ out) {
    int idx = blockIdx.x * 256 + threadIdx.x;   // 65536
    int e = idx >> 9, j = idx & 511;
    out[j * EMBED + e] = __float2bfloat16(in[idx]);
}

// W_hh [K=512][N=512] -> wt [N=512][K=512] bf16
__global__ void k_txp_whh(const float* __restrict__ in, bf16* __restrict__ out) {
    int idx = blockIdx.x * 256 + threadIdx.x;   // 262144
    int k = idx >> 9, n = idx & 511;
    out[n * HIDDEN + k] = __float2bfloat16(in[idx]);
}

// ---------------- bf16 MFMA GEMM:  C[M][N] = A[M][K] * B'[N][K]^T + bias ----------------
template<bool GATHER, bool OUT_BF16>
__global__ __launch_bounds__(256) void k_gemm(
    const bf16* __restrict__ A,       // [M][K]; if GATHER: embedding table [VOCAB][K]
    const int*  __restrict__ xtok,    // tokens [BATCH][SEQ] (GATHER only)
    const bf16* __restrict__ B,       // [N][K]
    const float* __restrict__ bias,   // [N]
    float* __restrict__ Cf,
    bf16*  __restrict__ Cb,
    int M, int N, int K)
{
    __shared__ bf16 As[64][72];
    __shared__ bf16 Bs[64][72];
    const int m0 = blockIdx.x * 64, n0 = blockIdx.y * 64;
    const int tid  = threadIdx.x;
    const int lane = tid & 63, wid = tid >> 6;
    const int wm = wid >> 1, wn = wid & 1;
    const int lrow = tid >> 3, lc8 = tid & 7;

    f32x4 acc[2][2] = {};

    for (int k0 = 0; k0 < K; k0 += 64) {
#pragma unroll
        for (int pass = 0; pass < 2; ++pass) {
            int row = pass * 32 + lrow;
            const bf16* asrc;
            if (GATHER) {
                int m = m0 + row;                 // m = t*BATCH + b
                int t = m >> 6, bb = m & 63;
                int tok = xtok[bb * SEQ + t];
                asrc = A + (size_t)tok * K + k0 + lc8 * 8;
            } else {
                asrc = A + (size_t)(m0 + row) * K + k0 + lc8 * 8;
            }
            *reinterpret_cast<uint4*>(&As[row][lc8 * 8]) = *reinterpret_cast<const uint4*>(asrc);
            *reinterpret_cast<uint4*>(&Bs[row][lc8 * 8]) =
                *reinterpret_cast<const uint4*>(B + (size_t)(n0 + row) * K + k0 + lc8 * 8);
        }
        __syncthreads();
#pragma unroll
        for (int kk = 0; kk < 2; ++kk) {
            bf16x8 af[2], bg[2];
#pragma unroll
            for (int mt = 0; mt < 2; ++mt)
                af[mt] = *reinterpret_cast<const bf16x8*>(
                    &As[wm * 32 + mt * 16 + (lane & 15)][kk * 32 + (lane >> 4) * 8]);
#pragma unroll
            for (int nt = 0; nt < 2; ++nt)
                bg[nt] = *reinterpret_cast<const bf16x8*>(
                    &Bs[wn * 32 + nt * 16 + (lane & 15)][kk * 32 + (lane >> 4) * 8]);
#pragma unroll
            for (int mt = 0; mt < 2; ++mt)
#pragma unroll
                for (int nt = 0; nt < 2; ++nt)
                    acc[mt][nt] = __builtin_amdgcn_mfma_f32_16x16x32_bf16(
                        af[mt], bg[nt], acc[mt][nt], 0, 0, 0);
        }
        __syncthreads();
    }
#pragma unroll
    for (int mt = 0; mt < 2; ++mt) {
        int rbase = m0 + wm * 32 + mt * 16 + (lane >> 4) * 4;
#pragma unroll
        for (int nt = 0; nt < 2; ++nt) {
            int col = n0 + wn * 32 + nt * 16 + (lane & 15);
            float bv = bias[col];
#pragma unroll
            for (int r = 0; r < 4; ++r) {
                float v = acc[mt][nt][r] + bv;
                size_t off = (size_t)(rbase + r) * N + col;
                if (OUT_BF16) Cb[off] = __float2bfloat16(v);
                else          Cf[off] = v;
            }
        }
    }
}

// ---------------- MFMA scan: 4 blocks x 16 rows, 16 waves x 32 N-cols ----------------
// SWAPPED operands: acc = mfma(A=W_frag, B=h_frag, acc) -> D layout (b=lane&15,
// n=(lane>>4)*4+r): each thread owns 4 CONSECUTIVE n-cols of one batch row.
//   epilogue: 2 x ds_write_b64 (vs 16 scattered b16); hh stored DIRECT from regs;
//   xw read row-major b64 (no permuted staging buffer at all).
// ALL 16 W chunks register-pinned: 128 regs/wave; 16 waves -> 872/2048 per SIMD.
// h in LDS identity fragment order, CSTR=584: af reads octet-linear conflict-free
// (R10-verified); epilogue b64 writes ~2-way (free per m136).
#define ROWS 16
#define GSTR 72       // group stride in bf16 (64 data + 8 pad)
#define CSTR 584      // chunk stride in bf16 (292 dw == 4 mod 32)

__global__ __launch_bounds__(1024, 4) void k_scan_mfma(
    const bf16* __restrict__ xw,    // [SEQ*BATCH][HIDDEN] row-major (m = t*64+b)
    const bf16* __restrict__ wt,    // [HIDDEN n][HIDDEN k]
    const float* __restrict__ h0,   // [BATCH][HIDDEN]
    bf16* __restrict__ hh,          // [BATCH][SEQ][HIDDEN]
    float* __restrict__ hfin)       // [BATCH][HIDDEN]
{
    __shared__ bf16 hp[2][16 * CSTR];        // 2 x 18.25 KB

    const int tid  = threadIdx.x;
    const int lane = tid & 63, wid = tid >> 6;    // 16 waves
    const int b0   = blockIdx.x * ROWS;
    const int scol = wid * 32;                    // wave's 32-col slice
    const int lm   = lane & 15, lk = lane >> 4;   // lk in 0..3

    // af read offset: block = lane (identity, conflict-free octet-linear)
    const int gofs = (lane >> 3) * GSTR + (lane & 7) * 8;

    // ownership: b = b0+lm; cols c0(nt) = scol + nt*16 + lk*4 .. +3  (kc = wid)
    int wofs[2];
#pragma unroll
    for (int nt = 0; nt < 2; ++nt) {
        int c0 = scol + nt * 16 + lk * 4;
        int l1 = ((c0 & 31) >> 3) * 16 + lm;          // future reading lane
        wofs[nt] = wid * CSTR + (l1 >> 3) * GSTR + (l1 & 7) * 8 + (c0 & 7);
    }

    // ---- one-time: h0 -> hp[0] (mirror of epilogue write path) ----
#pragma unroll
    for (int nt = 0; nt < 2; ++nt) {
        int c0 = scol + nt * 16 + lk * 4;
        float4 v = *reinterpret_cast<const float4*>(
            h0 + (size_t)(b0 + lm) * HIDDEN + c0);
        bf16 h4[4] = { __float2bfloat16(v.x), __float2bfloat16(v.y),
                       __float2bfloat16(v.z), __float2bfloat16(v.w) };
        *reinterpret_cast<uint2*>(&hp[0][wofs[nt]]) = *reinterpret_cast<uint2*>(h4);
    }

    // ---- one-time: ALL 16 W chunks -> registers (128/wave), pinned vs remat ----
    bf16x8 breg[16][2];
#pragma unroll
    for (int c = 0; c < 16; ++c)
#pragma unroll
        for (int nt = 0; nt < 2; ++nt) {
            breg[c][nt] = *reinterpret_cast<const bf16x8*>(
                wt + (size_t)(scol + nt * 16 + lm) * HIDDEN + c * 32 + lk * 8);
            asm volatile("" : "+v"(breg[c][nt]));   // opaque: no remat
        }

    const bf16* xbase = xw + ((size_t)b0 + lm) * HIDDEN + scol + lk * 4;
    bf16* hbase = hh + (size_t)(b0 + lm) * SEQ * HIDDEN + scol + lk * 4;

    __syncthreads();

    int p = 0;
    for (int t = 0; t < SEQ; ++t) {
        // xw for this step: 2 x b64, issued early (row-major, L2-resident)
        const bf16* xrow = xbase + (size_t)t * BATCH * HIDDEN;
        uint2 xv0 = *reinterpret_cast<const uint2*>(xrow);
        uint2 xv1 = *reinterpret_cast<const uint2*>(xrow + 16);

        // MFMA: A = W fragments (regs), B = h fragments (LDS, conflict-free)
        f32x4 acc[2] = {};
#pragma unroll
        for (int kc = 0; kc < 16; ++kc) {
            bf16x8 af = *reinterpret_cast<const bf16x8*>(&hp[p][kc * CSTR + gofs]);
            acc[0] = __builtin_amdgcn_mfma_f32_16x16x32_bf16(breg[kc][0], af, acc[0], 0, 0, 0);
            acc[1] = __builtin_amdgcn_mfma_f32_16x16x32_bf16(breg[kc][1], af, acc[1], 0, 0, 0);
        }

        // epilogue: D(b=lm, n=c0+r) -> tanh -> b64 to hp[p^1] + b64 to hh (direct)
        const ushort* xu[2] = { reinterpret_cast<const ushort*>(&xv0),
                                reinterpret_cast<const ushort*>(&xv1) };
#pragma unroll
        for (int nt = 0; nt < 2; ++nt) {
            bf16 h4[4];
#pragma unroll
            for (int r = 0; r < 4; ++r) {
                float pre = acc[nt][r] + bfu(xu[nt][r]);
                float e2  = __expf(2.f * pre);
                float rc  = __builtin_amdgcn_rcpf(e2 + 1.f);
                float hn  = fmaf(-2.f, rc, 1.f);        // tanh(pre)
                h4[r] = __float2bfloat16(hn);
                if (t == SEQ - 1)
                    hfin[(size_t)(b0 + lm) * HIDDEN + scol + nt * 16 + lk * 4 + r] = hn;
            }
            *reinterpret_cast<uint2*>(&hp[p ^ 1][wofs[nt]]) = *reinterpret_cast<uint2*>(h4);
            *reinterpret_cast<uint2*>(hbase + (size_t)t * HIDDEN + nt * 16) =
                *reinterpret_cast<uint2*>(h4);
        }
        p ^= 1;
        __syncthreads();    // single barrier per step
    }
}

// ---------------- launch ----------------
extern "C" void kernel_launch(void* const* d_in, const int* in_sizes, int n_in,
                              void* d_out, int out_size, void* d_ws, size_t ws_size,
                              hipStream_t stream) {
    const int*   x    = (const int*)  d_in[0];
    const float* h0   = (const float*)d_in[1];
    const float* emb  = (const float*)d_in[2];
    const float* wxh  = (const float*)d_in[3];
    const float* whh  = (const float*)d_in[4];
    const float* bh   = (const float*)d_in[5];
    const float* whyw = (const float*)d_in[6];
    const float* whyb = (const float*)d_in[7];

    float* logits = (float*)d_out;                            // [BATCH][SEQ][VOCAB]
    float* hfin   = logits + (size_t)BATCH * SEQ * VOCAB;     // [BATCH][HIDDEN]

    char* p = (char*)d_ws;
    bf16* xwb    = (bf16*)p; p += (size_t)SEQ * BATCH * HIDDEN * 2;
    bf16* hh     = (bf16*)p; p += (size_t)BATCH * SEQ * HIDDEN * 2;
    bf16* wt     = (bf16*)p; p += (size_t)HIDDEN * HIDDEN * 2;
    bf16* wxh_t  = (bf16*)p; p += (size_t)HIDDEN * EMBED * 2;
    bf16* emb_bf = (bf16*)p; p += (size_t)VOCAB * EMBED * 2;
    bf16* why_bf = (bf16*)p; p += (size_t)VOCAB * HIDDEN * 2;

    k_txp_whh<<<(HIDDEN * HIDDEN + 255) / 256, 256, 0, stream>>>(whh, wt);
    k_cvt<<<(VOCAB * EMBED + 255) / 256, 256, 0, stream>>>(emb, emb_bf, VOCAB * EMBED);
    k_cvt<<<(VOCAB * HIDDEN + 255) / 256, 256, 0, stream>>>(whyw, why_bf, VOCAB * HIDDEN);
    k_txp_wxh<<<(EMBED * HIDDEN + 255) / 256, 256, 0, stream>>>(wxh, wxh_t);

    // phase 1: xwb[t*64+b][j] = emb[x[b][t]] @ W_xh + b_h  (plain row-major bf16)
    k_gemm<true, true><<<dim3((SEQ * BATCH) / 64, HIDDEN / 64), 256, 0, stream>>>(
        emb_bf, x, wxh_t, bh, nullptr, xwb, SEQ * BATCH, HIDDEN, EMBED);

    // phase 2: the recurrence (4 blocks x 16 batch rows, 1024 threads / 16 waves)
    k_scan_mfma<<<BATCH / ROWS, 1024, 0, stream>>>(xwb, wt, h0, hh, hfin);

    // phase 3: logits = hh @ W_hy^T + b
    k_gemm<false, false><<<dim3((BATCH * SEQ) / 64, VOCAB / 64), 256, 0, stream>>>(
        hh, nullptr, why_bf, whyb, logits, nullptr, BATCH * SEQ, VOCAB, HIDDEN);
}